// Round 15
// baseline (264.176 us; speedup 1.0000x reference)
//
#include <hip/hip_runtime.h>
#include <math.h>

// MMGCN: both GEMMs pushed through the (linear) aggregations, conv1+conv2 FUSED (LDS
// hand-off), gathers in 8-lane row-groups (8 rows/wave, 32B/lane/edge, unroll-4 ->
// 128B in flight per lane).
//   z1 = A.(xn*onrm)                       -> agg1
//   k_conv: phase 1 conv1 (K=128,N=256 paired) -> out[:,128:256] + Qs (LDS, swizzled);
//           phase 2 q = [qin0 | Qs] @ W2 (K=384) -> q bf16
//   out[:,256:384] = agg(q)*in_norm + 0.5(b1v+b1t) + gid  -> agg2e
// GEMM staging: global_load_lds (16B DMA), linear LDS dest + pre-swizzled source (rule #21).

typedef unsigned int uint;
typedef unsigned short ushort;
using bf16x8 = __attribute__((ext_vector_type(8))) short;
using f32x4  = __attribute__((ext_vector_type(4))) float;

__device__ __forceinline__ float lrelu(float v) { return v >= 0.0f ? v : 0.01f * v; }
__device__ __forceinline__ float bf2f(uint us) { return __uint_as_float(us << 16); }
__device__ __forceinline__ ushort f2bf(float f) {
    uint u = __float_as_uint(f);
    u += 0x7fffu + ((u >> 16) & 1u);   // round-to-nearest-even
    return (ushort)(u >> 16);
}
__device__ __forceinline__ void stage16(const ushort* g, ushort* l) {
    __builtin_amdgcn_global_load_lds(
        (const __attribute__((address_space(1))) void*)(g),
        (__attribute__((address_space(3))) void*)(l), 16, 0, 0);
}
__device__ __forceinline__ void acc8(uint4 v, float* a) {
    a[0] += bf2f(v.x & 0xffffu); a[1] += bf2f(v.x >> 16);
    a[2] += bf2f(v.y & 0xffffu); a[3] += bf2f(v.y >> 16);
    a[4] += bf2f(v.z & 0xffffu); a[5] += bf2f(v.z >> 16);
    a[6] += bf2f(v.w & 0xffffu); a[7] += bf2f(v.w >> 16);
}

// ---------------- degrees + weight prep (merged; first 192 blocks do wprep) ----------
// W1T [256 rows][128 k]: row h*128+p: p<64 -> Wv0 col (h*64+p); p>=64 -> Wt0 col
// W2T [128 rows][384 k]: k 0:128 = 0.5(Wv1+Wt1); k 128+2q+b = 0.5 Wb1[128+q]
__global__ void k_degprep(const int* __restrict__ src, const int* __restrict__ dst,
                          int* __restrict__ deg_out, int* __restrict__ deg_in, int E,
                          const float* __restrict__ Wv0, const float* __restrict__ Wt0,
                          const float* __restrict__ Wv1, const float* __restrict__ Wt1,
                          const float* __restrict__ bv0, const float* __restrict__ bt0,
                          const float* __restrict__ bv1, const float* __restrict__ bt1,
                          ushort* __restrict__ W1T, ushort* __restrict__ W2T,
                          float* __restrict__ bias_cat, float* __restrict__ bias2) {
    if (blockIdx.x < 192) {
        int t = blockIdx.x * 256 + threadIdx.x;
        if (t < 256 * 128) {
            int cp = t >> 7, k = t & 127;
            int p = cp & 127;
            int col = ((cp >> 7) << 6) + (p & 63);
            float v = (p < 64) ? Wv0[k * 128 + col] : Wt0[k * 128 + col];
            W1T[cp * 128 + k] = f2bf(v);
        }
        if (t < 128 * 384) {
            int c = t / 384, r = t % 384;
            float v;
            if (r < 128) v = 0.5f * (Wv1[r * 128 + c] + Wt1[r * 128 + c]);
            else {
                int q = (r - 128) >> 1;
                v = 0.5f * (((r - 128) & 1) ? Wt1[(128 + q) * 128 + c] : Wv1[(128 + q) * 128 + c]);
            }
            W2T[c * 384 + r] = f2bf(v);
        }
        if (t < 256) {
            int p = t & 127;
            int col = ((t >> 7) << 6) + (p & 63);
            bias_cat[t] = (p < 64) ? bv0[col] : bt0[col];
        }
        if (t < 128) bias2[t] = 0.5f * (bv1[t] + bt1[t]);
    } else {
        int e = (blockIdx.x - 192) * 256 + threadIdx.x;
        if (e < E) {
            atomicAdd(&deg_out[src[e]], 1);
            atomicAdd(&deg_in[dst[e]], 1);
        }
    }
}

// ---------------- scan1 (+ norms fused): per-1024-chunk inclusive scan of deg_in ------
__global__ void k_scan1(const int* __restrict__ deg_out, const int* __restrict__ deg_in,
                        int* __restrict__ row_ptr, int* __restrict__ csum,
                        float* __restrict__ onrm, float* __restrict__ inrm, int n) {
    __shared__ int wsum[16];
    __shared__ int wpre[16];
    int lane = threadIdx.x & 63;
    int wid  = threadIdx.x >> 6;
    int i = blockIdx.x * 1024 + threadIdx.x;
    int v = (i < n) ? deg_in[i] : 0;
    if (i < n) {
        onrm[i] = 1.0f / sqrtf((float)max(deg_out[i], 1));
        inrm[i] = 1.0f / sqrtf((float)max(v, 1));
    }
    int s = v;
    #pragma unroll
    for (int off = 1; off < 64; off <<= 1) {
        int t = __shfl_up(s, off, 64);
        if (lane >= off) s += t;
    }
    if (lane == 63) wsum[wid] = s;
    __syncthreads();
    if (wid == 0) {
        int wv = (lane < 16) ? wsum[lane] : 0;
        int ss = wv;
        #pragma unroll
        for (int off = 1; off < 16; off <<= 1) {
            int t = __shfl_up(ss, off, 64);
            if (lane >= off) ss += t;
        }
        if (lane < 16) wpre[lane] = ss - wv;
    }
    __syncthreads();
    int incl = s + wpre[wid];
    if (i < n) row_ptr[i + 1] = incl;                        // chunk-local for now
    if (threadIdx.x == 1023) csum[blockIdx.x] = incl;        // chunk total
}

__global__ void k_scan2(int* __restrict__ csum, int nb) {
    __shared__ int wsum[16];
    __shared__ int wpre[16];
    int lane = threadIdx.x & 63;
    int wid  = threadIdx.x >> 6;
    int i = threadIdx.x;
    int v = (i < nb) ? csum[i] : 0;
    int s = v;
    #pragma unroll
    for (int off = 1; off < 64; off <<= 1) {
        int t = __shfl_up(s, off, 64);
        if (lane >= off) s += t;
    }
    if (lane == 63) wsum[wid] = s;
    __syncthreads();
    if (wid == 0) {
        int wv = (lane < 16) ? wsum[lane] : 0;
        int ss = wv;
        #pragma unroll
        for (int off = 1; off < 16; off <<= 1) {
            int t = __shfl_up(ss, off, 64);
            if (lane >= off) ss += t;
        }
        if (lane < 16) wpre[lane] = ss - wv;
    }
    __syncthreads();
    if (i < nb) csum[i] = s + wpre[wid];
}

// scan3: finalize row_ptr and materialize cursor = row_ptr (absolute fill cursors)
__global__ void k_scan3(int* __restrict__ row_ptr, const int* __restrict__ csum,
                        int* __restrict__ cursor, int n) {
    int i = blockIdx.x * blockDim.x + threadIdx.x;
    if (i == 0) { row_ptr[0] = 0; cursor[0] = 0; }
    if (i < n) {
        int b = i >> 10;
        int rv = row_ptr[i + 1] + ((b > 0) ? csum[b - 1] : 0);
        row_ptr[i + 1] = rv;
        if (i + 1 < n) cursor[i + 1] = rv;
    }
}

__global__ void k_fill(const int* __restrict__ src, const int* __restrict__ dst,
                       int* __restrict__ cursor, int* __restrict__ col, int E) {
    int e = blockIdx.x * blockDim.x + threadIdx.x;
    if (e < E) {
        int pos = atomicAdd(&cursor[dst[e]], 1);
        col[pos] = src[e];
    }
}

// --- row L2-normalize x (16-lane groups); out[:,0:128]=leaky(xn); xn_sc=xn*onrm;
//     qin0 = leaky(xn_sc) [N][128]; gid = id_emb[dst_ids] densified (bf16) ---
__global__ void k_normx(const float* __restrict__ x, const float* __restrict__ onrm,
                        const int* __restrict__ dsti, const float* __restrict__ id_emb,
                        ushort* __restrict__ xn_sc, ushort* __restrict__ qin0,
                        ushort* __restrict__ gid, float* __restrict__ out, int n) {
    int gtid = blockIdx.x * blockDim.x + threadIdx.x;
    int row  = gtid >> 4;
    int lane = gtid & 15;
    if (row >= n) return;
    int c = lane * 8;
    float4 v0 = *(const float4*)&x[(size_t)row * 128 + c];
    float4 v1 = *(const float4*)&x[(size_t)row * 128 + c + 4];
    float s = v0.x * v0.x + v0.y * v0.y + v0.z * v0.z + v0.w * v0.w
            + v1.x * v1.x + v1.y * v1.y + v1.z * v1.z + v1.w * v1.w;
    #pragma unroll
    for (int off = 1; off < 16; off <<= 1) s += __shfl_xor(s, off, 64);
    float scale = 1.0f / fmaxf(sqrtf(s), 1e-12f);
    float nx[8] = {v0.x * scale, v0.y * scale, v0.z * scale, v0.w * scale,
                   v1.x * scale, v1.y * scale, v1.z * scale, v1.w * scale};
    *(float4*)&out[(size_t)row * 384 + c] =
        make_float4(lrelu(nx[0]), lrelu(nx[1]), lrelu(nx[2]), lrelu(nx[3]));
    *(float4*)&out[(size_t)row * 384 + c + 4] =
        make_float4(lrelu(nx[4]), lrelu(nx[5]), lrelu(nx[6]), lrelu(nx[7]));
    float so = onrm[row];
    float sx[8];
    #pragma unroll
    for (int j = 0; j < 8; j++) sx[j] = nx[j] * so;
    uint4 px = make_uint4((uint)f2bf(sx[0]) | ((uint)f2bf(sx[1]) << 16),
                          (uint)f2bf(sx[2]) | ((uint)f2bf(sx[3]) << 16),
                          (uint)f2bf(sx[4]) | ((uint)f2bf(sx[5]) << 16),
                          (uint)f2bf(sx[6]) | ((uint)f2bf(sx[7]) << 16));
    *(uint4*)&xn_sc[(size_t)row * 128 + c] = px;
    uint4 pq = make_uint4((uint)f2bf(lrelu(sx[0])) | ((uint)f2bf(lrelu(sx[1])) << 16),
                          (uint)f2bf(lrelu(sx[2])) | ((uint)f2bf(lrelu(sx[3])) << 16),
                          (uint)f2bf(lrelu(sx[4])) | ((uint)f2bf(lrelu(sx[5])) << 16),
                          (uint)f2bf(lrelu(sx[6])) | ((uint)f2bf(lrelu(sx[7])) << 16));
    *(uint4*)&qin0[(size_t)row * 128 + c] = pq;
    int g = dsti[row];
    float4 g0 = *(const float4*)&id_emb[(size_t)g * 128 + c];
    float4 g1 = *(const float4*)&id_emb[(size_t)g * 128 + c + 4];
    uint4 pg = make_uint4((uint)f2bf(g0.x) | ((uint)f2bf(g0.y) << 16),
                          (uint)f2bf(g0.z) | ((uint)f2bf(g0.w) << 16),
                          (uint)f2bf(g1.x) | ((uint)f2bf(g1.y) << 16),
                          (uint)f2bf(g1.z) | ((uint)f2bf(g1.w) << 16));
    *(uint4*)&gid[(size_t)row * 128 + c] = pg;
}

// ------- gather pass 1: z1 = A.xn_sc  (8-lane groups, 32B/lane/edge, unroll 4/2/1) -----
__global__ void k_agg1(const ushort* __restrict__ xn_sc, const int* __restrict__ rp,
                       const int* __restrict__ col, ushort* __restrict__ z1, int n) {
    int gtid = blockIdx.x * blockDim.x + threadIdx.x;
    int row  = gtid >> 3;
    int lane = gtid & 7;
    if (row >= n) return;
    int c = lane * 16;                            // 16 bf16 = 32B per lane
    float a[16];
    #pragma unroll
    for (int j = 0; j < 16; j++) a[j] = 0.f;
    int e = rp[row], e1 = rp[row + 1];
    for (; e + 3 < e1; e += 4) {
        int s0 = col[e], s1 = col[e + 1], s2 = col[e + 2], s3 = col[e + 3];
        uint4 u0a = *(const uint4*)&xn_sc[(size_t)s0 * 128 + c];
        uint4 u0b = *(const uint4*)&xn_sc[(size_t)s0 * 128 + c + 8];
        uint4 u1a = *(const uint4*)&xn_sc[(size_t)s1 * 128 + c];
        uint4 u1b = *(const uint4*)&xn_sc[(size_t)s1 * 128 + c + 8];
        uint4 u2a = *(const uint4*)&xn_sc[(size_t)s2 * 128 + c];
        uint4 u2b = *(const uint4*)&xn_sc[(size_t)s2 * 128 + c + 8];
        uint4 u3a = *(const uint4*)&xn_sc[(size_t)s3 * 128 + c];
        uint4 u3b = *(const uint4*)&xn_sc[(size_t)s3 * 128 + c + 8];
        acc8(u0a, a); acc8(u0b, a + 8);
        acc8(u1a, a); acc8(u1b, a + 8);
        acc8(u2a, a); acc8(u2b, a + 8);
        acc8(u3a, a); acc8(u3b, a + 8);
    }
    if (e + 1 < e1) {
        int s0 = col[e], s1 = col[e + 1];
        uint4 u0a = *(const uint4*)&xn_sc[(size_t)s0 * 128 + c];
        uint4 u0b = *(const uint4*)&xn_sc[(size_t)s0 * 128 + c + 8];
        uint4 u1a = *(const uint4*)&xn_sc[(size_t)s1 * 128 + c];
        uint4 u1b = *(const uint4*)&xn_sc[(size_t)s1 * 128 + c + 8];
        acc8(u0a, a); acc8(u0b, a + 8);
        acc8(u1a, a); acc8(u1b, a + 8);
        e += 2;
    }
    if (e < e1) {
        int s0 = col[e];
        uint4 u0a = *(const uint4*)&xn_sc[(size_t)s0 * 128 + c];
        uint4 u0b = *(const uint4*)&xn_sc[(size_t)s0 * 128 + c + 8];
        acc8(u0a, a); acc8(u0b, a + 8);
    }
    uint4 p0 = make_uint4((uint)f2bf(a[0]) | ((uint)f2bf(a[1]) << 16),
                          (uint)f2bf(a[2]) | ((uint)f2bf(a[3]) << 16),
                          (uint)f2bf(a[4]) | ((uint)f2bf(a[5]) << 16),
                          (uint)f2bf(a[6]) | ((uint)f2bf(a[7]) << 16));
    uint4 p1 = make_uint4((uint)f2bf(a[8])  | ((uint)f2bf(a[9])  << 16),
                          (uint)f2bf(a[10]) | ((uint)f2bf(a[11]) << 16),
                          (uint)f2bf(a[12]) | ((uint)f2bf(a[13]) << 16),
                          (uint)f2bf(a[14]) | ((uint)f2bf(a[15]) << 16));
    *(uint4*)&z1[(size_t)row * 128 + c]     = p0;
    *(uint4*)&z1[(size_t)row * 128 + c + 8] = p1;
}

// --- gather pass 2 + conv2 epilogue (8-lane groups, unroll 4/2/1) ---
__global__ void k_agg2e(const ushort* __restrict__ q, const int* __restrict__ rp,
                        const int* __restrict__ col, const float* __restrict__ inrm,
                        const float* __restrict__ bias2, const ushort* __restrict__ gid,
                        float* __restrict__ out, int n) {
    int gtid = blockIdx.x * blockDim.x + threadIdx.x;
    int row  = gtid >> 3;
    int lane = gtid & 7;
    if (row >= n) return;
    int c = lane * 16;
    float a[16];
    #pragma unroll
    for (int j = 0; j < 16; j++) a[j] = 0.f;
    int e = rp[row], e1 = rp[row + 1];
    for (; e + 3 < e1; e += 4) {
        int s0 = col[e], s1 = col[e + 1], s2 = col[e + 2], s3 = col[e + 3];
        uint4 u0a = *(const uint4*)&q[(size_t)s0 * 128 + c];
        uint4 u0b = *(const uint4*)&q[(size_t)s0 * 128 + c + 8];
        uint4 u1a = *(const uint4*)&q[(size_t)s1 * 128 + c];
        uint4 u1b = *(const uint4*)&q[(size_t)s1 * 128 + c + 8];
        uint4 u2a = *(const uint4*)&q[(size_t)s2 * 128 + c];
        uint4 u2b = *(const uint4*)&q[(size_t)s2 * 128 + c + 8];
        uint4 u3a = *(const uint4*)&q[(size_t)s3 * 128 + c];
        uint4 u3b = *(const uint4*)&q[(size_t)s3 * 128 + c + 8];
        acc8(u0a, a); acc8(u0b, a + 8);
        acc8(u1a, a); acc8(u1b, a + 8);
        acc8(u2a, a); acc8(u2b, a + 8);
        acc8(u3a, a); acc8(u3b, a + 8);
    }
    if (e + 1 < e1) {
        int s0 = col[e], s1 = col[e + 1];
        uint4 u0a = *(const uint4*)&q[(size_t)s0 * 128 + c];
        uint4 u0b = *(const uint4*)&q[(size_t)s0 * 128 + c + 8];
        uint4 u1a = *(const uint4*)&q[(size_t)s1 * 128 + c];
        uint4 u1b = *(const uint4*)&q[(size_t)s1 * 128 + c + 8];
        acc8(u0a, a); acc8(u0b, a + 8);
        acc8(u1a, a); acc8(u1b, a + 8);
        e += 2;
    }
    if (e < e1) {
        int s0 = col[e];
        uint4 u0a = *(const uint4*)&q[(size_t)s0 * 128 + c];
        uint4 u0b = *(const uint4*)&q[(size_t)s0 * 128 + c + 8];
        acc8(u0a, a); acc8(u0b, a + 8);
    }
    float win = inrm[row];
    uint4 pgA = *(const uint4*)&gid[(size_t)row * 128 + c];
    uint4 pgB = *(const uint4*)&gid[(size_t)row * 128 + c + 8];
    float gg[16] = {bf2f(pgA.x & 0xffffu), bf2f(pgA.x >> 16),
                    bf2f(pgA.y & 0xffffu), bf2f(pgA.y >> 16),
                    bf2f(pgA.z & 0xffffu), bf2f(pgA.z >> 16),
                    bf2f(pgA.w & 0xffffu), bf2f(pgA.w >> 16),
                    bf2f(pgB.x & 0xffffu), bf2f(pgB.x >> 16),
                    bf2f(pgB.y & 0xffffu), bf2f(pgB.y >> 16),
                    bf2f(pgB.z & 0xffffu), bf2f(pgB.z >> 16),
                    bf2f(pgB.w & 0xffffu), bf2f(pgB.w >> 16)};
    #pragma unroll
    for (int h = 0; h < 4; h++) {
        float4 bi = *(const float4*)&bias2[c + h * 4];
        float4 o;
        o.x = a[h * 4 + 0] * win + bi.x + gg[h * 4 + 0];
        o.y = a[h * 4 + 1] * win + bi.y + gg[h * 4 + 1];
        o.z = a[h * 4 + 2] * win + bi.z + gg[h * 4 + 2];
        o.w = a[h * 4 + 3] * win + bi.w + gg[h * 4 + 3];
        *(float4*)&out[(size_t)row * 384 + 256 + c + h * 4] = o;
    }
}

// ---- fused conv kernel: 64 rows/block, 512 threads (8 waves, 2x4) ----
// Phase 1: conv1 (K=128, N=256 paired) from z1/W1T; epilogue -> out[:,128:256] + Qs (LDS).
// Phase 2: q = [qin0 | Qs] @ W2 (K=384, N=128), W2 double-buffered; q bf16 out.
__global__ __launch_bounds__(512) void k_conv(
    const ushort* __restrict__ z1, const ushort* __restrict__ W1T,
    const ushort* __restrict__ qin0, const ushort* __restrict__ W2T,
    const float* __restrict__ inrm, const float* __restrict__ onrm,
    const ushort* __restrict__ gid, const float* __restrict__ bias_cat,
    ushort* __restrict__ q, float* __restrict__ out, int n)
{
    __shared__ __align__(16) ushort As[2 * 64 * 64];   // 16KB: A tiles (2 halves)
    __shared__ __align__(16) ushort Bs[256 * 64];      // 32KB: p1 full W1T step; p2 2x16KB halves
    __shared__ __align__(16) ushort Qs[64 * 256];      // 32KB: qin cols 128:384, swizzled
    int tid  = threadIdx.x;
    int lane = tid & 63;
    int w    = tid >> 6;            // 0..7
    int wm   = w >> 2, wn = w & 3;
    int lr   = lane & 15, lk = lane >> 4;
    int row0 = blockIdx.x * 64;
    int sw   = lr & 7;
    int h    = wn >> 1;             // phase-1 pair geometry
    int pbase = (wn & 1) * 32;

    // A-staging granule for this thread (64x64 tile = 512 granules, 1/thread)
    int gA = w * 64 + lane;
    int rA = gA >> 3, lcA = gA & 7;
    int scolA = ((lcA ^ (rA & 7)) << 3);
    int dA = gA * 8;

    // ---------------- phase 1: conv1 ----------------
    f32x4 acc[2][4];
    f32x4 zero = {0.f, 0.f, 0.f, 0.f};
    #pragma unroll
    for (int m = 0; m < 2; m++)
        #pragma unroll
        for (int nn = 0; nn < 4; nn++) acc[m][nn] = zero;

    const ushort* aSrc1 = z1 + (size_t)(row0 + rA) * 128 + scolA;
    for (int ks = 0; ks < 2; ks++) {
        stage16(aSrc1 + ks * 64, As + ks * 4096 + dA);
        #pragma unroll
        for (int c = 0; c < 4; c++) {
            int gB = w * 256 + c * 64 + lane;
            int rB = gB >> 3, lcB = gB & 7;
            stage16(W1T + (size_t)rB * 128 + ks * 64 + ((lcB ^ (rB & 7)) << 3), Bs + gB * 8);
        }
        __syncthreads();
        const char* ab = (const char*)(As + ks * 4096);
        const char* bb = (const char*)Bs;
        #pragma unroll
        for (int kk = 0; kk < 2; kk++) {
            int kx = (((kk * 4 + lk) ^ sw) << 4);
            bf16x8 af[2], bf[4];
            #pragma unroll
            for (int m = 0; m < 2; m++) {
                int r = wm * 32 + m * 16 + lr;
                af[m] = *(const bf16x8*)(ab + r * 128 + kx);
            }
            #pragma unroll
            for (int nn = 0; nn < 2; nn++) {
                int vrow = h * 128 + pbase + nn * 16 + lr;
                bf[nn]     = *(const bf16x8*)(bb + vrow * 128 + kx);
                bf[nn + 2] = *(const bf16x8*)(bb + (vrow + 64) * 128 + kx);
            }
            #pragma unroll
            for (int m = 0; m < 2; m++)
                #pragma unroll
                for (int nn = 0; nn < 4; nn++)
                    acc[m][nn] = __builtin_amdgcn_mfma_f32_16x16x32_bf16(af[m], bf[nn], acc[m][nn], 0, 0, 0);
        }
        __syncthreads();
    }

    // ---------------- phase-1 epilogue: out[:,128:256] + Qs (swizzled LDS) ----------------
    #pragma unroll
    for (int m = 0; m < 2; m++) {
        int rloc0 = wm * 32 + m * 16 + lk * 4;
        #pragma unroll
        for (int nn = 0; nn < 2; nn++) {
            int po = pbase + nn * 16 + lr;
            int cv = h * 64 + po;                 // pair/v-col 0..127
            float biv = bias_cat[h * 128 + po];
            float bit = bias_cat[h * 128 + 64 + po];
            #pragma unroll
            for (int j = 0; j < 4; j++) {
                int rl = rloc0 + j;
                int r  = row0 + rl;
                float lv = 0.f, lt = 0.f;
                if (r < n) {
                    float win = inrm[r];
                    float won = onrm[r];
                    float ge = bf2f((uint)gid[(size_t)r * 128 + cv]);
                    float tv = acc[m][nn][j] * win + biv + ge;
                    float tt = acc[m][nn + 2][j] * win + bit + ge;
                    lv = lrelu(tv); lt = lrelu(tt);
                    out[(size_t)r * 384 + 128 + cv] = 0.5f * (lv + lt);
                    lv *= won; lt *= won;
                }
                uint pk = (uint)f2bf(lv) | ((uint)f2bf(lt) << 16);
                *(uint*)((char*)Qs + ((rl * 512 + 4 * cv) ^ ((rl & 7) << 4))) = pk;
            }
        }
    }
    // prestage phase 2: qin0 k-steps 0,1 into As halves; W2T step 0 into Bs half0
    const ushort* aSrc0 = qin0 + (size_t)(row0 + rA) * 128 + scolA;
    stage16(aSrc0,      As + dA);
    stage16(aSrc0 + 64, As + 4096 + dA);
    #pragma unroll
    for (int c = 0; c < 2; c++) {
        int g2 = w * 128 + c * 64 + lane;
        int r2 = g2 >> 3, lc2 = g2 & 7;
        stage16(W2T + (size_t)r2 * 384 + ((lc2 ^ (r2 & 7)) << 3), Bs + g2 * 8);
    }
    __syncthreads();   // Qs ds_writes + DMA staged all visible

    // ---------------- phase 2: q = [qin0 | Qs] @ W2, K=384 ----------------
    f32x4 acc2[2][2];
    #pragma unroll
    for (int m = 0; m < 2; m++)
        #pragma unroll
        for (int nn = 0; nn < 2; nn++) acc2[m][nn] = zero;

    for (int s = 0; s < 6; s++) {
        if (s < 5) {                              // stage next W2 k-step into other half
            int nh = (s + 1) & 1;
            #pragma unroll
            for (int c = 0; c < 2; c++) {
                int g2 = w * 128 + c * 64 + lane;
                int r2 = g2 >> 3, lc2 = g2 & 7;
                stage16(W2T + (size_t)r2 * 384 + (s + 1) * 64 + ((lc2 ^ (r2 & 7)) << 3),
                        Bs + nh * 8192 + g2 * 8);
            }
        }
        const char* bb2 = (const char*)(Bs + (s & 1) * 8192);
        #pragma unroll
        for (int kk = 0; kk < 2; kk++) {
            int kx = (((kk * 4 + lk) ^ sw) << 4);
            bf16x8 af[2], bf[2];
            #pragma unroll
            for (int m = 0; m < 2; m++) {
                int rl = wm * 32 + m * 16 + lr;
                if (s < 2)
                    af[m] = *(const bf16x8*)((const char*)(As + s * 4096) + rl * 128 + kx);
                else
                    af[m] = *(const bf16x8*)((const char*)Qs +
                              ((rl * 512 + (s - 2) * 128 + (kk * 4 + lk) * 16) ^ ((rl & 7) << 4)));
            }
            #pragma unroll
            for (int nn = 0; nn < 2; nn++) {
                int cg = wn * 32 + nn * 16 + lr;
                bf[nn] = *(const bf16x8*)(bb2 + cg * 128 + kx);
            }
            #pragma unroll
            for (int m = 0; m < 2; m++)
                #pragma unroll
                for (int nn = 0; nn < 2; nn++)
                    acc2[m][nn] = __builtin_amdgcn_mfma_f32_16x16x32_bf16(af[m], bf[nn], acc2[m][nn], 0, 0, 0);
        }
        __syncthreads();   // next-step staging visible; this step's Bs reads done
    }

    // ---------------- phase-2 epilogue: q (bf16) ----------------
    #pragma unroll
    for (int m = 0; m < 2; m++) {
        int rb = row0 + wm * 32 + m * 16 + lk * 4;
        #pragma unroll
        for (int nn = 0; nn < 2; nn++) {
            int cg = wn * 32 + nn * 16 + lr;
            #pragma unroll
            for (int j = 0; j < 4; j++) {
                int r = rb + j;
                if (r < n) q[(size_t)r * 128 + cg] = f2bf(acc2[m][nn][j]);
            }
        }
    }
}

extern "C" void kernel_launch(void* const* d_in, const int* in_sizes, int n_in,
                              void* d_out, int out_size, void* d_ws, size_t ws_size,
                              hipStream_t stream) {
    const float* x      = (const float*)d_in[0];
    const float* id_emb = (const float*)d_in[1];
    const float* Wv0    = (const float*)d_in[2];
    const float* bv0    = (const float*)d_in[3];
    const float* Wv1    = (const float*)d_in[4];
    const float* bv1    = (const float*)d_in[5];
    const float* Wt0    = (const float*)d_in[6];
    const float* bt0    = (const float*)d_in[7];
    const float* Wt1    = (const float*)d_in[8];
    const float* bt1    = (const float*)d_in[9];
    const int*   src    = (const int*)d_in[10];
    const int*   dst    = (const int*)d_in[11];
    const int*   dsti   = (const int*)d_in[12];
    const int E = in_sizes[10];
    const int N = in_sizes[12];
    float* out = (float*)d_out;

    char* p = (char*)d_ws;
    ushort* xn_sc   = (ushort*)p; p += (size_t)N * 128 * 2;
    ushort* qin0    = (ushort*)p; p += (size_t)N * 128 * 2;
    ushort* z1      = (ushort*)p; p += (size_t)N * 128 * 2;
    ushort* q       = (ushort*)p; p += (size_t)N * 128 * 2;
    ushort* gid     = (ushort*)p; p += (size_t)N * 128 * 2;
    ushort* W1T     = (ushort*)p; p += 256 * 128 * 2;
    ushort* W2T     = (ushort*)p; p += 128 * 384 * 2;
    float* bias_cat = (float*)p;  p += 256 * 4;
    float* bias2    = (float*)p;  p += 128 * 4;
    float* onrm     = (float*)p;  p += (size_t)N * 4;
    float* inrm     = (float*)p;  p += (size_t)N * 4;
    int* deg_out    = (int*)p;    p += (size_t)N * 4;
    int* deg_in     = (int*)p;    p += (size_t)N * 4;
    int* cursor     = (int*)p;    p += (size_t)N * 4;
    int* row_ptr    = (int*)p;    p += (size_t)(N + 1) * 4;
    int* csum       = (int*)p;    p += 1024 * 4;
    int* col        = (int*)p;    p += (size_t)E * 4;

    hipMemsetAsync(deg_out, 0, (size_t)N * 2 * 4, stream);   // deg_out|deg_in contiguous

    int be = (E + 255) / 256;
    int bn = (N + 255) / 256;
    int bq = (N * 16 + 255) / 256;          // 16-lane groups (normx)
    int b8 = (N * 8 + 255) / 256;           // 8-lane groups (gathers)
    int bc = (N + 63) / 64;                 // 64-row fused-conv tiles
    int nb = (N + 1023) / 1024;             // scan chunks

    k_degprep<<<192 + be, 256, 0, stream>>>(src, dst, deg_out, deg_in, E,
                                            Wv0, Wt0, Wv1, Wt1, bv0, bt0, bv1, bt1,
                                            W1T, W2T, bias_cat, bias2);
    k_scan1  <<<nb, 1024, 0, stream>>>(deg_out, deg_in, row_ptr, csum, onrm, inrm, N);
    k_scan2  <<<1, 1024, 0, stream>>>(csum, nb);
    k_scan3  <<<bn, 256, 0, stream>>>(row_ptr, csum, cursor, N);
    k_fill   <<<be, 256, 0, stream>>>(src, dst, cursor, col, E);
    k_normx  <<<bq, 256, 0, stream>>>(x, onrm, dsti, id_emb, xn_sc, qin0, gid, out, N);

    k_agg1 <<<b8, 256, 0, stream>>>(xn_sc, row_ptr, col, z1, N);
    k_conv <<<bc, 512, 0, stream>>>(z1, W1T, qin0, W2T, inrm, onrm, gid,
                                    bias_cat, q, out, N);
    k_agg2e<<<b8, 256, 0, stream>>>(q, row_ptr, col, inrm, bias2, gid, out, N);
}

// Round 16
// 251.428 us; speedup vs baseline: 1.0507x; 1.0507x over previous
//
#include <hip/hip_runtime.h>
#include <math.h>

// MMGCN: GEMMs pushed through the aggregations; conv1+conv2+agg1 all FUSED in k_conv:
//   k_conv per 64-row block:
//     phase 0: gather z1 tile (A.(xn*onrm)) for its rows straight into LDS (swizzled)
//     phase 1: conv1 = z1 @ W1T (K=128, N=256 v/t-paired) -> out[:,128:256] + Qs (LDS)
//     phase 2: q = [qin0 | Qs] @ W2 (K=384) -> q bf16
//   out[:,256:384] = agg(q)*in_norm + 0.5(b1v+b1t) + gid  -> agg2e (16-lane groups)
// Gathers are L3-BW-bound (rounds 13/15 nulls) -> fusing at lower occupancy is ~free,
// and deletes the z1 global round-trip. GEMM staging: global_load_lds, rule #21 swizzle.

typedef unsigned int uint;
typedef unsigned short ushort;
using bf16x8 = __attribute__((ext_vector_type(8))) short;
using f32x4  = __attribute__((ext_vector_type(4))) float;

__device__ __forceinline__ float lrelu(float v) { return v >= 0.0f ? v : 0.01f * v; }
__device__ __forceinline__ float bf2f(uint us) { return __uint_as_float(us << 16); }
__device__ __forceinline__ ushort f2bf(float f) {
    uint u = __float_as_uint(f);
    u += 0x7fffu + ((u >> 16) & 1u);   // round-to-nearest-even
    return (ushort)(u >> 16);
}
__device__ __forceinline__ void stage16(const ushort* g, ushort* l) {
    __builtin_amdgcn_global_load_lds(
        (const __attribute__((address_space(1))) void*)(g),
        (__attribute__((address_space(3))) void*)(l), 16, 0, 0);
}
__device__ __forceinline__ void acc8(uint4 v, float* a) {
    a[0] += bf2f(v.x & 0xffffu); a[1] += bf2f(v.x >> 16);
    a[2] += bf2f(v.y & 0xffffu); a[3] += bf2f(v.y >> 16);
    a[4] += bf2f(v.z & 0xffffu); a[5] += bf2f(v.z >> 16);
    a[6] += bf2f(v.w & 0xffffu); a[7] += bf2f(v.w >> 16);
}

// ---------------- degrees + weight prep (merged; first 192 blocks do wprep) ----------
__global__ void k_degprep(const int* __restrict__ src, const int* __restrict__ dst,
                          int* __restrict__ deg_out, int* __restrict__ deg_in, int E,
                          const float* __restrict__ Wv0, const float* __restrict__ Wt0,
                          const float* __restrict__ Wv1, const float* __restrict__ Wt1,
                          const float* __restrict__ bv0, const float* __restrict__ bt0,
                          const float* __restrict__ bv1, const float* __restrict__ bt1,
                          ushort* __restrict__ W1T, ushort* __restrict__ W2T,
                          float* __restrict__ bias_cat, float* __restrict__ bias2) {
    if (blockIdx.x < 192) {
        int t = blockIdx.x * 256 + threadIdx.x;
        if (t < 256 * 128) {
            int cp = t >> 7, k = t & 127;
            int p = cp & 127;
            int col = ((cp >> 7) << 6) + (p & 63);
            float v = (p < 64) ? Wv0[k * 128 + col] : Wt0[k * 128 + col];
            W1T[cp * 128 + k] = f2bf(v);
        }
        if (t < 128 * 384) {
            int c = t / 384, r = t % 384;
            float v;
            if (r < 128) v = 0.5f * (Wv1[r * 128 + c] + Wt1[r * 128 + c]);
            else {
                int q = (r - 128) >> 1;
                v = 0.5f * (((r - 128) & 1) ? Wt1[(128 + q) * 128 + c] : Wv1[(128 + q) * 128 + c]);
            }
            W2T[c * 384 + r] = f2bf(v);
        }
        if (t < 256) {
            int p = t & 127;
            int col = ((t >> 7) << 6) + (p & 63);
            bias_cat[t] = (p < 64) ? bv0[col] : bt0[col];
        }
        if (t < 128) bias2[t] = 0.5f * (bv1[t] + bt1[t]);
    } else {
        int e = (blockIdx.x - 192) * 256 + threadIdx.x;
        if (e < E) {
            atomicAdd(&deg_out[src[e]], 1);
            atomicAdd(&deg_in[dst[e]], 1);
        }
    }
}

// ---------------- scan1 (+ norms fused): per-1024-chunk inclusive scan of deg_in ------
__global__ void k_scan1(const int* __restrict__ deg_out, const int* __restrict__ deg_in,
                        int* __restrict__ row_ptr, int* __restrict__ csum,
                        float* __restrict__ onrm, float* __restrict__ inrm, int n) {
    __shared__ int wsum[16];
    __shared__ int wpre[16];
    int lane = threadIdx.x & 63;
    int wid  = threadIdx.x >> 6;
    int i = blockIdx.x * 1024 + threadIdx.x;
    int v = (i < n) ? deg_in[i] : 0;
    if (i < n) {
        onrm[i] = 1.0f / sqrtf((float)max(deg_out[i], 1));
        inrm[i] = 1.0f / sqrtf((float)max(v, 1));
    }
    int s = v;
    #pragma unroll
    for (int off = 1; off < 64; off <<= 1) {
        int t = __shfl_up(s, off, 64);
        if (lane >= off) s += t;
    }
    if (lane == 63) wsum[wid] = s;
    __syncthreads();
    if (wid == 0) {
        int wv = (lane < 16) ? wsum[lane] : 0;
        int ss = wv;
        #pragma unroll
        for (int off = 1; off < 16; off <<= 1) {
            int t = __shfl_up(ss, off, 64);
            if (lane >= off) ss += t;
        }
        if (lane < 16) wpre[lane] = ss - wv;
    }
    __syncthreads();
    int incl = s + wpre[wid];
    if (i < n) row_ptr[i + 1] = incl;                        // chunk-local for now
    if (threadIdx.x == 1023) csum[blockIdx.x] = incl;        // RAW chunk total
}

// scan3 (merged scan2): each block reduces its own chunk prefix over csum[0..b-1]
// (blocks of 256 never straddle a 1024-chunk), then finalizes row_ptr and cursor.
__global__ void k_scan3(int* __restrict__ row_ptr, const int* __restrict__ csum,
                        int* __restrict__ cursor, int n) {
    __shared__ int spre;
    int b = (int)((blockIdx.x * 256) >> 10);
    if (threadIdx.x < 64) {
        int acc = 0;
        for (int k = (int)threadIdx.x; k < b; k += 64) acc += csum[k];
        #pragma unroll
        for (int off = 1; off < 64; off <<= 1) acc += __shfl_xor(acc, off, 64);
        if (threadIdx.x == 0) spre = acc;
    }
    __syncthreads();
    int pre = spre;
    int i = blockIdx.x * 256 + threadIdx.x;
    if (i == 0) { row_ptr[0] = 0; cursor[0] = 0; }
    if (i < n) {
        int rv = row_ptr[i + 1] + pre;
        row_ptr[i + 1] = rv;
        if (i + 1 < n) cursor[i + 1] = rv;
    }
}

__global__ void k_fill(const int* __restrict__ src, const int* __restrict__ dst,
                       int* __restrict__ cursor, int* __restrict__ col, int E) {
    int e = blockIdx.x * blockDim.x + threadIdx.x;
    if (e < E) {
        int pos = atomicAdd(&cursor[dst[e]], 1);
        col[pos] = src[e];
    }
}

// --- row L2-normalize x (16-lane groups); out[:,0:128]=leaky(xn); xn_sc=xn*onrm;
//     qin0 = leaky(xn_sc) [N][128]; gid = id_emb[dst_ids] densified (bf16) ---
__global__ void k_normx(const float* __restrict__ x, const float* __restrict__ onrm,
                        const int* __restrict__ dsti, const float* __restrict__ id_emb,
                        ushort* __restrict__ xn_sc, ushort* __restrict__ qin0,
                        ushort* __restrict__ gid, float* __restrict__ out, int n) {
    int gtid = blockIdx.x * blockDim.x + threadIdx.x;
    int row  = gtid >> 4;
    int lane = gtid & 15;
    if (row >= n) return;
    int c = lane * 8;
    float4 v0 = *(const float4*)&x[(size_t)row * 128 + c];
    float4 v1 = *(const float4*)&x[(size_t)row * 128 + c + 4];
    float s = v0.x * v0.x + v0.y * v0.y + v0.z * v0.z + v0.w * v0.w
            + v1.x * v1.x + v1.y * v1.y + v1.z * v1.z + v1.w * v1.w;
    #pragma unroll
    for (int off = 1; off < 16; off <<= 1) s += __shfl_xor(s, off, 64);
    float scale = 1.0f / fmaxf(sqrtf(s), 1e-12f);
    float nx[8] = {v0.x * scale, v0.y * scale, v0.z * scale, v0.w * scale,
                   v1.x * scale, v1.y * scale, v1.z * scale, v1.w * scale};
    *(float4*)&out[(size_t)row * 384 + c] =
        make_float4(lrelu(nx[0]), lrelu(nx[1]), lrelu(nx[2]), lrelu(nx[3]));
    *(float4*)&out[(size_t)row * 384 + c + 4] =
        make_float4(lrelu(nx[4]), lrelu(nx[5]), lrelu(nx[6]), lrelu(nx[7]));
    float so = onrm[row];
    float sx[8];
    #pragma unroll
    for (int j = 0; j < 8; j++) sx[j] = nx[j] * so;
    uint4 px = make_uint4((uint)f2bf(sx[0]) | ((uint)f2bf(sx[1]) << 16),
                          (uint)f2bf(sx[2]) | ((uint)f2bf(sx[3]) << 16),
                          (uint)f2bf(sx[4]) | ((uint)f2bf(sx[5]) << 16),
                          (uint)f2bf(sx[6]) | ((uint)f2bf(sx[7]) << 16));
    *(uint4*)&xn_sc[(size_t)row * 128 + c] = px;
    uint4 pq = make_uint4((uint)f2bf(lrelu(sx[0])) | ((uint)f2bf(lrelu(sx[1])) << 16),
                          (uint)f2bf(lrelu(sx[2])) | ((uint)f2bf(lrelu(sx[3])) << 16),
                          (uint)f2bf(lrelu(sx[4])) | ((uint)f2bf(lrelu(sx[5])) << 16),
                          (uint)f2bf(lrelu(sx[6])) | ((uint)f2bf(lrelu(sx[7])) << 16));
    *(uint4*)&qin0[(size_t)row * 128 + c] = pq;
    int g = dsti[row];
    float4 g0 = *(const float4*)&id_emb[(size_t)g * 128 + c];
    float4 g1 = *(const float4*)&id_emb[(size_t)g * 128 + c + 4];
    uint4 pg = make_uint4((uint)f2bf(g0.x) | ((uint)f2bf(g0.y) << 16),
                          (uint)f2bf(g0.z) | ((uint)f2bf(g0.w) << 16),
                          (uint)f2bf(g1.x) | ((uint)f2bf(g1.y) << 16),
                          (uint)f2bf(g1.z) | ((uint)f2bf(g1.w) << 16));
    *(uint4*)&gid[(size_t)row * 128 + c] = pg;
}

// --- gather pass 2 + conv2 epilogue (16-lane groups, unroll 4/2/1) ---
__global__ void k_agg2e(const ushort* __restrict__ q, const int* __restrict__ rp,
                        const int* __restrict__ col, const float* __restrict__ inrm,
                        const float* __restrict__ bias2, const ushort* __restrict__ gid,
                        float* __restrict__ out, int n) {
    int gtid = blockIdx.x * blockDim.x + threadIdx.x;
    int row  = gtid >> 4;
    int lane = gtid & 15;
    if (row >= n) return;
    int c = lane * 8;
    float a[8] = {0.f, 0.f, 0.f, 0.f, 0.f, 0.f, 0.f, 0.f};
    int e = rp[row], e1 = rp[row + 1];
    for (; e + 3 < e1; e += 4) {
        int s0 = col[e], s1 = col[e + 1], s2 = col[e + 2], s3 = col[e + 3];
        uint4 v0 = *(const uint4*)&q[(size_t)s0 * 128 + c];
        uint4 v1 = *(const uint4*)&q[(size_t)s1 * 128 + c];
        uint4 v2 = *(const uint4*)&q[(size_t)s2 * 128 + c];
        uint4 v3 = *(const uint4*)&q[(size_t)s3 * 128 + c];
        acc8(v0, a); acc8(v1, a); acc8(v2, a); acc8(v3, a);
    }
    if (e + 1 < e1) {
        int s0 = col[e], s1 = col[e + 1];
        uint4 v0 = *(const uint4*)&q[(size_t)s0 * 128 + c];
        uint4 v1 = *(const uint4*)&q[(size_t)s1 * 128 + c];
        acc8(v0, a); acc8(v1, a);
        e += 2;
    }
    if (e < e1) {
        uint4 v0 = *(const uint4*)&q[(size_t)col[e] * 128 + c];
        acc8(v0, a);
    }
    float win = inrm[row];
    float4 b0 = *(const float4*)&bias2[c];
    float4 b1 = *(const float4*)&bias2[c + 4];
    uint4 pg = *(const uint4*)&gid[(size_t)row * 128 + c];
    float4 o0, o1;
    o0.x = a[0] * win + b0.x + bf2f(pg.x & 0xffffu);
    o0.y = a[1] * win + b0.y + bf2f(pg.x >> 16);
    o0.z = a[2] * win + b0.z + bf2f(pg.y & 0xffffu);
    o0.w = a[3] * win + b0.w + bf2f(pg.y >> 16);
    o1.x = a[4] * win + b1.x + bf2f(pg.z & 0xffffu);
    o1.y = a[5] * win + b1.y + bf2f(pg.z >> 16);
    o1.z = a[6] * win + b1.z + bf2f(pg.w & 0xffffu);
    o1.w = a[7] * win + b1.w + bf2f(pg.w >> 16);
    *(float4*)&out[(size_t)row * 384 + 256 + c]     = o0;
    *(float4*)&out[(size_t)row * 384 + 256 + c + 4] = o1;
}

// ---- fused conv kernel: 64 rows/block, 512 threads (8 waves, 2x4) ----
// Phase 0: gather z1 tile into As[64 rows][256B] (XOR-swizzled ds_write).
// Phase 1: conv1 (K=128, N=256 paired); epilogue -> out[:,128:256] + Qs (LDS).
// Phase 2: q = [qin0 | Qs] @ W2 (K=384, N=128), W2 double-buffered; q bf16 out.
__global__ __launch_bounds__(512) void k_conv(
    const ushort* __restrict__ xn_sc, const int* __restrict__ rp,
    const int* __restrict__ col, const ushort* __restrict__ W1T,
    const ushort* __restrict__ qin0, const ushort* __restrict__ W2T,
    const float* __restrict__ inrm, const float* __restrict__ onrm,
    const ushort* __restrict__ gid, const float* __restrict__ bias_cat,
    ushort* __restrict__ q, float* __restrict__ out, int n)
{
    __shared__ __align__(16) ushort As[2 * 64 * 64];   // 16KB; p0/p1: [64][256B] z1; p2: 2x8KB qin0
    __shared__ __align__(16) ushort Bs[256 * 64];      // 32KB
    __shared__ __align__(16) ushort Qs[64 * 256];      // 32KB
    int tid  = threadIdx.x;
    int lane = tid & 63;
    int w    = tid >> 6;            // 0..7
    int wm   = w >> 2, wn = w & 3;
    int lr   = lane & 15, lk = lane >> 4;
    int row0 = blockIdx.x * 64;
    int sw   = lr & 7;
    int h    = wn >> 1;             // phase-1 pair geometry
    int pbase = (wn & 1) * 32;

    // ---------------- phase 0: gather z1 tile -> As (swizzled [64][2x128B]) -------------
    {
        int rl = tid >> 3;           // 0..63, one row per 8-lane group
        int l  = tid & 7;
        int c  = l * 16;             // 16 bf16 = 32B per lane
        float a[16];
        #pragma unroll
        for (int j = 0; j < 16; j++) a[j] = 0.f;
        int r = row0 + rl;
        if (r < n) {
            int e = rp[r], e1 = rp[r + 1];
            for (; e + 3 < e1; e += 4) {
                int s0 = col[e], s1 = col[e + 1], s2 = col[e + 2], s3 = col[e + 3];
                uint4 u0a = *(const uint4*)&xn_sc[(size_t)s0 * 128 + c];
                uint4 u0b = *(const uint4*)&xn_sc[(size_t)s0 * 128 + c + 8];
                uint4 u1a = *(const uint4*)&xn_sc[(size_t)s1 * 128 + c];
                uint4 u1b = *(const uint4*)&xn_sc[(size_t)s1 * 128 + c + 8];
                uint4 u2a = *(const uint4*)&xn_sc[(size_t)s2 * 128 + c];
                uint4 u2b = *(const uint4*)&xn_sc[(size_t)s2 * 128 + c + 8];
                uint4 u3a = *(const uint4*)&xn_sc[(size_t)s3 * 128 + c];
                uint4 u3b = *(const uint4*)&xn_sc[(size_t)s3 * 128 + c + 8];
                acc8(u0a, a); acc8(u0b, a + 8);
                acc8(u1a, a); acc8(u1b, a + 8);
                acc8(u2a, a); acc8(u2b, a + 8);
                acc8(u3a, a); acc8(u3b, a + 8);
            }
            if (e + 1 < e1) {
                int s0 = col[e], s1 = col[e + 1];
                uint4 u0a = *(const uint4*)&xn_sc[(size_t)s0 * 128 + c];
                uint4 u0b = *(const uint4*)&xn_sc[(size_t)s0 * 128 + c + 8];
                uint4 u1a = *(const uint4*)&xn_sc[(size_t)s1 * 128 + c];
                uint4 u1b = *(const uint4*)&xn_sc[(size_t)s1 * 128 + c + 8];
                acc8(u0a, a); acc8(u0b, a + 8);
                acc8(u1a, a); acc8(u1b, a + 8);
                e += 2;
            }
            if (e < e1) {
                int s0 = col[e];
                uint4 u0a = *(const uint4*)&xn_sc[(size_t)s0 * 128 + c];
                uint4 u0b = *(const uint4*)&xn_sc[(size_t)s0 * 128 + c + 8];
                acc8(u0a, a); acc8(u0b, a + 8);
            }
        }
        uint4 p0 = make_uint4((uint)f2bf(a[0]) | ((uint)f2bf(a[1]) << 16),
                              (uint)f2bf(a[2]) | ((uint)f2bf(a[3]) << 16),
                              (uint)f2bf(a[4]) | ((uint)f2bf(a[5]) << 16),
                              (uint)f2bf(a[6]) | ((uint)f2bf(a[7]) << 16));
        uint4 p1 = make_uint4((uint)f2bf(a[8])  | ((uint)f2bf(a[9])  << 16),
                              (uint)f2bf(a[10]) | ((uint)f2bf(a[11]) << 16),
                              (uint)f2bf(a[12]) | ((uint)f2bf(a[13]) << 16),
                              (uint)f2bf(a[14]) | ((uint)f2bf(a[15]) << 16));
        // granules G=2l, 2l+1 of row rl; ks = G>>3, gi = G&7; swizzle gi ^= rl&7
        int G0 = 2 * l, G1 = 2 * l + 1;
        char* base = (char*)As + rl * 256;
        *(uint4*)(base + (G0 >> 3) * 128 + (((G0 & 7) ^ (rl & 7)) << 4)) = p0;
        *(uint4*)(base + (G1 >> 3) * 128 + (((G1 & 7) ^ (rl & 7)) << 4)) = p1;
    }
    // (phase-1's first __syncthreads makes the gathered tile visible before reads)

    // ---------------- phase 1: conv1 ----------------
    f32x4 acc[2][4];
    f32x4 zero = {0.f, 0.f, 0.f, 0.f};
    #pragma unroll
    for (int m = 0; m < 2; m++)
        #pragma unroll
        for (int nn = 0; nn < 4; nn++) acc[m][nn] = zero;

    for (int ks = 0; ks < 2; ks++) {
        #pragma unroll
        for (int c = 0; c < 4; c++) {
            int gB = w * 256 + c * 64 + lane;
            int rB = gB >> 3, lcB = gB & 7;
            stage16(W1T + (size_t)rB * 128 + ks * 64 + ((lcB ^ (rB & 7)) << 3), Bs + gB * 8);
        }
        __syncthreads();
        const char* ab = (const char*)As;
        const char* bb = (const char*)Bs;
        #pragma unroll
        for (int kk = 0; kk < 2; kk++) {
            int kx = (((kk * 4 + lk) ^ sw) << 4);
            bf16x8 af[2], bf[4];
            #pragma unroll
            for (int m = 0; m < 2; m++) {
                int r = wm * 32 + m * 16 + lr;
                af[m] = *(const bf16x8*)(ab + r * 256 + ks * 128 + kx);
            }
            #pragma unroll
            for (int nn = 0; nn < 2; nn++) {
                int vrow = h * 128 + pbase + nn * 16 + lr;
                bf[nn]     = *(const bf16x8*)(bb + vrow * 128 + kx);
                bf[nn + 2] = *(const bf16x8*)(bb + (vrow + 64) * 128 + kx);
            }
            #pragma unroll
            for (int m = 0; m < 2; m++)
                #pragma unroll
                for (int nn = 0; nn < 4; nn++)
                    acc[m][nn] = __builtin_amdgcn_mfma_f32_16x16x32_bf16(af[m], bf[nn], acc[m][nn], 0, 0, 0);
        }
        __syncthreads();
    }

    // ---------------- phase-1 epilogue: out[:,128:256] + Qs (swizzled LDS) ----------------
    #pragma unroll
    for (int m = 0; m < 2; m++) {
        int rloc0 = wm * 32 + m * 16 + lk * 4;
        #pragma unroll
        for (int nn = 0; nn < 2; nn++) {
            int po = pbase + nn * 16 + lr;
            int cv = h * 64 + po;                 // pair/v-col 0..127
            float biv = bias_cat[h * 128 + po];
            float bit = bias_cat[h * 128 + 64 + po];
            #pragma unroll
            for (int j = 0; j < 4; j++) {
                int rl = rloc0 + j;
                int r  = row0 + rl;
                float lv = 0.f, lt = 0.f;
                if (r < n) {
                    float win = inrm[r];
                    float won = onrm[r];
                    float ge = bf2f((uint)gid[(size_t)r * 128 + cv]);
                    float tv = acc[m][nn][j] * win + biv + ge;
                    float tt = acc[m][nn + 2][j] * win + bit + ge;
                    lv = lrelu(tv); lt = lrelu(tt);
                    out[(size_t)r * 384 + 128 + cv] = 0.5f * (lv + lt);
                    lv *= won; lt *= won;
                }
                uint pk = (uint)f2bf(lv) | ((uint)f2bf(lt) << 16);
                *(uint*)((char*)Qs + ((rl * 512 + 4 * cv) ^ ((rl & 7) << 4))) = pk;
            }
        }
    }
    // prestage phase 2: qin0 k-steps 0,1 into As halves (old 2x8KB layout); W2T step 0
    int gA = w * 64 + lane;
    int rA = gA >> 3, lcA = gA & 7;
    int scolA = ((lcA ^ (rA & 7)) << 3);
    int dA = gA * 8;
    const ushort* aSrc0 = qin0 + (size_t)(row0 + rA) * 128 + scolA;
    stage16(aSrc0,      As + dA);
    stage16(aSrc0 + 64, As + 4096 + dA);
    #pragma unroll
    for (int c = 0; c < 2; c++) {
        int g2 = w * 128 + c * 64 + lane;
        int r2 = g2 >> 3, lc2 = g2 & 7;
        stage16(W2T + (size_t)r2 * 384 + ((lc2 ^ (r2 & 7)) << 3), Bs + g2 * 8);
    }
    __syncthreads();   // Qs ds_writes + DMA staged all visible

    // ---------------- phase 2: q = [qin0 | Qs] @ W2, K=384 ----------------
    f32x4 acc2[2][2];
    #pragma unroll
    for (int m = 0; m < 2; m++)
        #pragma unroll
        for (int nn = 0; nn < 2; nn++) acc2[m][nn] = zero;

    for (int s = 0; s < 6; s++) {
        if (s < 5) {                              // stage next W2 k-step into other half
            int nh = (s + 1) & 1;
            #pragma unroll
            for (int c = 0; c < 2; c++) {
                int g2 = w * 128 + c * 64 + lane;
                int r2 = g2 >> 3, lc2 = g2 & 7;
                stage16(W2T + (size_t)r2 * 384 + (s + 1) * 64 + ((lc2 ^ (r2 & 7)) << 3),
                        Bs + nh * 8192 + g2 * 8);
            }
        }
        const char* bb2 = (const char*)(Bs + (s & 1) * 8192);
        #pragma unroll
        for (int kk = 0; kk < 2; kk++) {
            int kx = (((kk * 4 + lk) ^ sw) << 4);
            bf16x8 af[2], bf[2];
            #pragma unroll
            for (int m = 0; m < 2; m++) {
                int rl = wm * 32 + m * 16 + lr;
                if (s < 2)
                    af[m] = *(const bf16x8*)((const char*)(As + s * 4096) + rl * 128 + kx);
                else
                    af[m] = *(const bf16x8*)((const char*)Qs +
                              ((rl * 512 + (s - 2) * 128 + (kk * 4 + lk) * 16) ^ ((rl & 7) << 4)));
            }
            #pragma unroll
            for (int nn = 0; nn < 2; nn++) {
                int cg = wn * 32 + nn * 16 + lr;
                bf[nn] = *(const bf16x8*)(bb2 + cg * 128 + kx);
            }
            #pragma unroll
            for (int m = 0; m < 2; m++)
                #pragma unroll
                for (int nn = 0; nn < 2; nn++)
                    acc2[m][nn] = __builtin_amdgcn_mfma_f32_16x16x32_bf16(af[m], bf[nn], acc2[m][nn], 0, 0, 0);
        }
        __syncthreads();   // next-step staging visible; this step's Bs reads done
    }

    // ---------------- phase-2 epilogue: q (bf16) ----------------
    #pragma unroll
    for (int m = 0; m < 2; m++) {
        int rb = row0 + wm * 32 + m * 16 + lk * 4;
        #pragma unroll
        for (int nn = 0; nn < 2; nn++) {
            int cg = wn * 32 + nn * 16 + lr;
            #pragma unroll
            for (int j = 0; j < 4; j++) {
                int r = rb + j;
                if (r < n) q[(size_t)r * 128 + cg] = f2bf(acc2[m][nn][j]);
            }
        }
    }
}

extern "C" void kernel_launch(void* const* d_in, const int* in_sizes, int n_in,
                              void* d_out, int out_size, void* d_ws, size_t ws_size,
                              hipStream_t stream) {
    const float* x      = (const float*)d_in[0];
    const float* id_emb = (const float*)d_in[1];
    const float* Wv0    = (const float*)d_in[2];
    const float* bv0    = (const float*)d_in[3];
    const float* Wv1    = (const float*)d_in[4];
    const float* bv1    = (const float*)d_in[5];
    const float* Wt0    = (const float*)d_in[6];
    const float* bt0    = (const float*)d_in[7];
    const float* Wt1    = (const float*)d_in[8];
    const float* bt1    = (const float*)d_in[9];
    const int*   src    = (const int*)d_in[10];
    const int*   dst    = (const int*)d_in[11];
    const int*   dsti   = (const int*)d_in[12];
    const int E = in_sizes[10];
    const int N = in_sizes[12];
    float* out = (float*)d_out;

    char* p = (char*)d_ws;
    ushort* xn_sc   = (ushort*)p; p += (size_t)N * 128 * 2;
    ushort* qin0    = (ushort*)p; p += (size_t)N * 128 * 2;
    ushort* q       = (ushort*)p; p += (size_t)N * 128 * 2;
    ushort* gid     = (ushort*)p; p += (size_t)N * 128 * 2;
    ushort* W1T     = (ushort*)p; p += 256 * 128 * 2;
    ushort* W2T     = (ushort*)p; p += 128 * 384 * 2;
    float* bias_cat = (float*)p;  p += 256 * 4;
    float* bias2    = (float*)p;  p += 128 * 4;
    float* onrm     = (float*)p;  p += (size_t)N * 4;
    float* inrm     = (float*)p;  p += (size_t)N * 4;
    int* deg_out    = (int*)p;    p += (size_t)N * 4;
    int* deg_in     = (int*)p;    p += (size_t)N * 4;
    int* cursor     = (int*)p;    p += (size_t)N * 4;
    int* row_ptr    = (int*)p;    p += (size_t)(N + 1) * 4;
    int* csum       = (int*)p;    p += 1024 * 4;
    int* col        = (int*)p;    p += (size_t)E * 4;

    hipMemsetAsync(deg_out, 0, (size_t)N * 2 * 4, stream);   // deg_out|deg_in contiguous

    int be = (E + 255) / 256;
    int bn = (N + 255) / 256;
    int bq = (N * 16 + 255) / 256;          // 16-lane groups (normx + agg2e)
    int bc = (N + 63) / 64;                 // 64-row fused-conv tiles
    int nb = (N + 1023) / 1024;             // scan chunks

    k_degprep<<<192 + be, 256, 0, stream>>>(src, dst, deg_out, deg_in, E,
                                            Wv0, Wt0, Wv1, Wt1, bv0, bt0, bv1, bt1,
                                            W1T, W2T, bias_cat, bias2);
    k_scan1  <<<nb, 1024, 0, stream>>>(deg_out, deg_in, row_ptr, csum, onrm, inrm, N);
    k_scan3  <<<bn, 256, 0, stream>>>(row_ptr, csum, cursor, N);
    k_fill   <<<be, 256, 0, stream>>>(src, dst, cursor, col, E);
    k_normx  <<<bq, 256, 0, stream>>>(x, onrm, dsti, id_emb, xn_sc, qin0, gid, out, N);

    k_conv <<<bc, 512, 0, stream>>>(xn_sc, row_ptr, col, W1T, qin0, W2T,
                                    inrm, onrm, gid, bias_cat, q, out, N);
    k_agg2e<<<bq, 256, 0, stream>>>(q, row_ptr, col, inrm, bias2, gid, out, N);
}

// Round 17
// 248.975 us; speedup vs baseline: 1.0611x; 1.0099x over previous
//
#include <hip/hip_runtime.h>
#include <math.h>

// MMGCN: GEMMs pushed through the aggregations; conv1+conv2+agg1 all FUSED in k_conv:
//   k_conv per 64-row block:
//     phase 0: gather z1 tile (A.(xn*onrm)) for its rows straight into LDS (swizzled)
//     phase 1: conv1 = z1 @ W1T (K=128, N=256 v/t-paired) -> out[:,128:256] + Qs (LDS)
//     phase 2: q = [lrelu(xn_sc) | Qs] @ W2 (K=384) -> q bf16
//              (first 128 k reg-staged from xn_sc with on-the-fly lrelu: no qin0 buffer)
//   out[:,256:384] = agg(q)*in_norm + 0.5(b1v+b1t) + gid  -> agg2e (16-lane groups)
// Gathers are L3-BW-bound (rounds 13/15 nulls) -> fusing at low occupancy is ~free.
// GEMM staging: global_load_lds (16B DMA), linear LDS dest + pre-swizzled source (rule #21).

typedef unsigned int uint;
typedef unsigned short ushort;
using bf16x8 = __attribute__((ext_vector_type(8))) short;
using f32x4  = __attribute__((ext_vector_type(4))) float;

__device__ __forceinline__ float lrelu(float v) { return v >= 0.0f ? v : 0.01f * v; }
__device__ __forceinline__ float bf2f(uint us) { return __uint_as_float(us << 16); }
__device__ __forceinline__ ushort f2bf(float f) {
    uint u = __float_as_uint(f);
    u += 0x7fffu + ((u >> 16) & 1u);   // round-to-nearest-even
    return (ushort)(u >> 16);
}
__device__ __forceinline__ void stage16(const ushort* g, ushort* l) {
    __builtin_amdgcn_global_load_lds(
        (const __attribute__((address_space(1))) void*)(g),
        (__attribute__((address_space(3))) void*)(l), 16, 0, 0);
}
__device__ __forceinline__ void acc8(uint4 v, float* a) {
    a[0] += bf2f(v.x & 0xffffu); a[1] += bf2f(v.x >> 16);
    a[2] += bf2f(v.y & 0xffffu); a[3] += bf2f(v.y >> 16);
    a[4] += bf2f(v.z & 0xffffu); a[5] += bf2f(v.z >> 16);
    a[6] += bf2f(v.w & 0xffffu); a[7] += bf2f(v.w >> 16);
}
__device__ __forceinline__ uint lrelu_pk(uint u) {
    float lo = lrelu(bf2f(u & 0xffffu));
    float hi = lrelu(bf2f(u >> 16));
    return (uint)f2bf(lo) | ((uint)f2bf(hi) << 16);
}

// ---------------- degrees + weight prep (merged; first 192 blocks do wprep) ----------
__global__ void k_degprep(const int* __restrict__ src, const int* __restrict__ dst,
                          int* __restrict__ deg_out, int* __restrict__ deg_in, int E,
                          const float* __restrict__ Wv0, const float* __restrict__ Wt0,
                          const float* __restrict__ Wv1, const float* __restrict__ Wt1,
                          const float* __restrict__ bv0, const float* __restrict__ bt0,
                          const float* __restrict__ bv1, const float* __restrict__ bt1,
                          ushort* __restrict__ W1T, ushort* __restrict__ W2T,
                          float* __restrict__ bias_cat, float* __restrict__ bias2) {
    if (blockIdx.x < 192) {
        int t = blockIdx.x * 256 + threadIdx.x;
        if (t < 256 * 128) {
            int cp = t >> 7, k = t & 127;
            int p = cp & 127;
            int col = ((cp >> 7) << 6) + (p & 63);
            float v = (p < 64) ? Wv0[k * 128 + col] : Wt0[k * 128 + col];
            W1T[cp * 128 + k] = f2bf(v);
        }
        if (t < 128 * 384) {
            int c = t / 384, r = t % 384;
            float v;
            if (r < 128) v = 0.5f * (Wv1[r * 128 + c] + Wt1[r * 128 + c]);
            else {
                int q = (r - 128) >> 1;
                v = 0.5f * (((r - 128) & 1) ? Wt1[(128 + q) * 128 + c] : Wv1[(128 + q) * 128 + c]);
            }
            W2T[c * 384 + r] = f2bf(v);
        }
        if (t < 256) {
            int p = t & 127;
            int col = ((t >> 7) << 6) + (p & 63);
            bias_cat[t] = (p < 64) ? bv0[col] : bt0[col];
        }
        if (t < 128) bias2[t] = 0.5f * (bv1[t] + bt1[t]);
    } else {
        int e = (blockIdx.x - 192) * 256 + threadIdx.x;
        if (e < E) {
            atomicAdd(&deg_out[src[e]], 1);
            atomicAdd(&deg_in[dst[e]], 1);
        }
    }
}

// ---------------- scan1 (+ norms fused): per-1024-chunk inclusive scan of deg_in ------
__global__ void k_scan1(const int* __restrict__ deg_out, const int* __restrict__ deg_in,
                        int* __restrict__ row_ptr, int* __restrict__ csum,
                        float* __restrict__ onrm, float* __restrict__ inrm, int n) {
    __shared__ int wsum[16];
    __shared__ int wpre[16];
    int lane = threadIdx.x & 63;
    int wid  = threadIdx.x >> 6;
    int i = blockIdx.x * 1024 + threadIdx.x;
    int v = (i < n) ? deg_in[i] : 0;
    if (i < n) {
        onrm[i] = 1.0f / sqrtf((float)max(deg_out[i], 1));
        inrm[i] = 1.0f / sqrtf((float)max(v, 1));
    }
    int s = v;
    #pragma unroll
    for (int off = 1; off < 64; off <<= 1) {
        int t = __shfl_up(s, off, 64);
        if (lane >= off) s += t;
    }
    if (lane == 63) wsum[wid] = s;
    __syncthreads();
    if (wid == 0) {
        int wv = (lane < 16) ? wsum[lane] : 0;
        int ss = wv;
        #pragma unroll
        for (int off = 1; off < 16; off <<= 1) {
            int t = __shfl_up(ss, off, 64);
            if (lane >= off) ss += t;
        }
        if (lane < 16) wpre[lane] = ss - wv;
    }
    __syncthreads();
    int incl = s + wpre[wid];
    if (i < n) row_ptr[i + 1] = incl;                        // chunk-local for now
    if (threadIdx.x == 1023) csum[blockIdx.x] = incl;        // RAW chunk total
}

// scan3 (merged scan2): each block reduces its own chunk prefix over csum[0..b-1]
__global__ void k_scan3(int* __restrict__ row_ptr, const int* __restrict__ csum,
                        int* __restrict__ cursor, int n) {
    __shared__ int spre;
    int b = (int)((blockIdx.x * 256) >> 10);
    if (threadIdx.x < 64) {
        int acc = 0;
        for (int k = (int)threadIdx.x; k < b; k += 64) acc += csum[k];
        #pragma unroll
        for (int off = 1; off < 64; off <<= 1) acc += __shfl_xor(acc, off, 64);
        if (threadIdx.x == 0) spre = acc;
    }
    __syncthreads();
    int pre = spre;
    int i = blockIdx.x * 256 + threadIdx.x;
    if (i == 0) { row_ptr[0] = 0; cursor[0] = 0; }
    if (i < n) {
        int rv = row_ptr[i + 1] + pre;
        row_ptr[i + 1] = rv;
        if (i + 1 < n) cursor[i + 1] = rv;
    }
}

__global__ void k_fill(const int* __restrict__ src, const int* __restrict__ dst,
                       int* __restrict__ cursor, int* __restrict__ col, int E) {
    int e = blockIdx.x * blockDim.x + threadIdx.x;
    if (e < E) {
        int pos = atomicAdd(&cursor[dst[e]], 1);
        col[pos] = src[e];
    }
}

// --- row L2-normalize x (16-lane groups); out[:,0:128]=leaky(xn); xn_sc=xn*onrm;
//     gid = id_emb[dst_ids] densified (bf16) ---
__global__ void k_normx(const float* __restrict__ x, const float* __restrict__ onrm,
                        const int* __restrict__ dsti, const float* __restrict__ id_emb,
                        ushort* __restrict__ xn_sc, ushort* __restrict__ gid,
                        float* __restrict__ out, int n) {
    int gtid = blockIdx.x * blockDim.x + threadIdx.x;
    int row  = gtid >> 4;
    int lane = gtid & 15;
    if (row >= n) return;
    int c = lane * 8;
    float4 v0 = *(const float4*)&x[(size_t)row * 128 + c];
    float4 v1 = *(const float4*)&x[(size_t)row * 128 + c + 4];
    float s = v0.x * v0.x + v0.y * v0.y + v0.z * v0.z + v0.w * v0.w
            + v1.x * v1.x + v1.y * v1.y + v1.z * v1.z + v1.w * v1.w;
    #pragma unroll
    for (int off = 1; off < 16; off <<= 1) s += __shfl_xor(s, off, 64);
    float scale = 1.0f / fmaxf(sqrtf(s), 1e-12f);
    float nx[8] = {v0.x * scale, v0.y * scale, v0.z * scale, v0.w * scale,
                   v1.x * scale, v1.y * scale, v1.z * scale, v1.w * scale};
    *(float4*)&out[(size_t)row * 384 + c] =
        make_float4(lrelu(nx[0]), lrelu(nx[1]), lrelu(nx[2]), lrelu(nx[3]));
    *(float4*)&out[(size_t)row * 384 + c + 4] =
        make_float4(lrelu(nx[4]), lrelu(nx[5]), lrelu(nx[6]), lrelu(nx[7]));
    float so = onrm[row];
    float sx[8];
    #pragma unroll
    for (int j = 0; j < 8; j++) sx[j] = nx[j] * so;
    uint4 px = make_uint4((uint)f2bf(sx[0]) | ((uint)f2bf(sx[1]) << 16),
                          (uint)f2bf(sx[2]) | ((uint)f2bf(sx[3]) << 16),
                          (uint)f2bf(sx[4]) | ((uint)f2bf(sx[5]) << 16),
                          (uint)f2bf(sx[6]) | ((uint)f2bf(sx[7]) << 16));
    *(uint4*)&xn_sc[(size_t)row * 128 + c] = px;
    int g = dsti[row];
    float4 g0 = *(const float4*)&id_emb[(size_t)g * 128 + c];
    float4 g1 = *(const float4*)&id_emb[(size_t)g * 128 + c + 4];
    uint4 pg = make_uint4((uint)f2bf(g0.x) | ((uint)f2bf(g0.y) << 16),
                          (uint)f2bf(g0.z) | ((uint)f2bf(g0.w) << 16),
                          (uint)f2bf(g1.x) | ((uint)f2bf(g1.y) << 16),
                          (uint)f2bf(g1.z) | ((uint)f2bf(g1.w) << 16));
    *(uint4*)&gid[(size_t)row * 128 + c] = pg;
}

// --- gather pass 2 + conv2 epilogue (16-lane groups, unroll 4/2/1) ---
__global__ void k_agg2e(const ushort* __restrict__ q, const int* __restrict__ rp,
                        const int* __restrict__ col, const float* __restrict__ inrm,
                        const float* __restrict__ bias2, const ushort* __restrict__ gid,
                        float* __restrict__ out, int n) {
    int gtid = blockIdx.x * blockDim.x + threadIdx.x;
    int row  = gtid >> 4;
    int lane = gtid & 15;
    if (row >= n) return;
    int c = lane * 8;
    float a[8] = {0.f, 0.f, 0.f, 0.f, 0.f, 0.f, 0.f, 0.f};
    int e = rp[row], e1 = rp[row + 1];
    for (; e + 3 < e1; e += 4) {
        int s0 = col[e], s1 = col[e + 1], s2 = col[e + 2], s3 = col[e + 3];
        uint4 v0 = *(const uint4*)&q[(size_t)s0 * 128 + c];
        uint4 v1 = *(const uint4*)&q[(size_t)s1 * 128 + c];
        uint4 v2 = *(const uint4*)&q[(size_t)s2 * 128 + c];
        uint4 v3 = *(const uint4*)&q[(size_t)s3 * 128 + c];
        acc8(v0, a); acc8(v1, a); acc8(v2, a); acc8(v3, a);
    }
    if (e + 1 < e1) {
        int s0 = col[e], s1 = col[e + 1];
        uint4 v0 = *(const uint4*)&q[(size_t)s0 * 128 + c];
        uint4 v1 = *(const uint4*)&q[(size_t)s1 * 128 + c];
        acc8(v0, a); acc8(v1, a);
        e += 2;
    }
    if (e < e1) {
        uint4 v0 = *(const uint4*)&q[(size_t)col[e] * 128 + c];
        acc8(v0, a);
    }
    float win = inrm[row];
    float4 b0 = *(const float4*)&bias2[c];
    float4 b1 = *(const float4*)&bias2[c + 4];
    uint4 pg = *(const uint4*)&gid[(size_t)row * 128 + c];
    float4 o0, o1;
    o0.x = a[0] * win + b0.x + bf2f(pg.x & 0xffffu);
    o0.y = a[1] * win + b0.y + bf2f(pg.x >> 16);
    o0.z = a[2] * win + b0.z + bf2f(pg.y & 0xffffu);
    o0.w = a[3] * win + b0.w + bf2f(pg.y >> 16);
    o1.x = a[4] * win + b1.x + bf2f(pg.z & 0xffffu);
    o1.y = a[5] * win + b1.y + bf2f(pg.z >> 16);
    o1.z = a[6] * win + b1.z + bf2f(pg.w & 0xffffu);
    o1.w = a[7] * win + b1.w + bf2f(pg.w >> 16);
    *(float4*)&out[(size_t)row * 384 + 256 + c]     = o0;
    *(float4*)&out[(size_t)row * 384 + 256 + c + 4] = o1;
}

// ---- fused conv kernel: 64 rows/block, 512 threads (8 waves, 2x4) ----
// Phase 0: gather z1 tile into As[64 rows][256B] (XOR-swizzled ds_write).
// Phase 1: conv1 (K=128, N=256 paired); epilogue -> out[:,128:256] + Qs (LDS).
// Phase 2: q = [lrelu(xn_sc) | Qs] @ W2 (K=384, N=128); first 128 k reg-staged with
//          on-the-fly lrelu (deletes the qin0 global buffer); W2 double-buffered.
__global__ __launch_bounds__(512) void k_conv(
    const ushort* __restrict__ xn_sc, const int* __restrict__ rp,
    const int* __restrict__ col, const ushort* __restrict__ W1T,
    const ushort* __restrict__ W2T,
    const float* __restrict__ inrm, const float* __restrict__ onrm,
    const ushort* __restrict__ gid, const float* __restrict__ bias_cat,
    ushort* __restrict__ q, float* __restrict__ out, int n)
{
    __shared__ __align__(16) ushort As[2 * 64 * 64];   // 16KB; p0/p1: [64][256B] z1; p2: 2x8KB lrelu(xn_sc)
    __shared__ __align__(16) ushort Bs[256 * 64];      // 32KB
    __shared__ __align__(16) ushort Qs[64 * 256];      // 32KB
    int tid  = threadIdx.x;
    int lane = tid & 63;
    int w    = tid >> 6;            // 0..7
    int wm   = w >> 2, wn = w & 3;
    int lr   = lane & 15, lk = lane >> 4;
    int row0 = blockIdx.x * 64;
    int sw   = lr & 7;
    int h    = wn >> 1;             // phase-1 pair geometry
    int pbase = (wn & 1) * 32;

    // ---------------- phase 0: gather z1 tile -> As (swizzled [64][2x128B]) -------------
    {
        int rl = tid >> 3;           // 0..63, one row per 8-lane group
        int l  = tid & 7;
        int c  = l * 16;             // 16 bf16 = 32B per lane
        float a[16];
        #pragma unroll
        for (int j = 0; j < 16; j++) a[j] = 0.f;
        int r = row0 + rl;
        if (r < n) {
            int e = rp[r], e1 = rp[r + 1];
            for (; e + 3 < e1; e += 4) {
                int s0 = col[e], s1 = col[e + 1], s2 = col[e + 2], s3 = col[e + 3];
                uint4 u0a = *(const uint4*)&xn_sc[(size_t)s0 * 128 + c];
                uint4 u0b = *(const uint4*)&xn_sc[(size_t)s0 * 128 + c + 8];
                uint4 u1a = *(const uint4*)&xn_sc[(size_t)s1 * 128 + c];
                uint4 u1b = *(const uint4*)&xn_sc[(size_t)s1 * 128 + c + 8];
                uint4 u2a = *(const uint4*)&xn_sc[(size_t)s2 * 128 + c];
                uint4 u2b = *(const uint4*)&xn_sc[(size_t)s2 * 128 + c + 8];
                uint4 u3a = *(const uint4*)&xn_sc[(size_t)s3 * 128 + c];
                uint4 u3b = *(const uint4*)&xn_sc[(size_t)s3 * 128 + c + 8];
                acc8(u0a, a); acc8(u0b, a + 8);
                acc8(u1a, a); acc8(u1b, a + 8);
                acc8(u2a, a); acc8(u2b, a + 8);
                acc8(u3a, a); acc8(u3b, a + 8);
            }
            if (e + 1 < e1) {
                int s0 = col[e], s1 = col[e + 1];
                uint4 u0a = *(const uint4*)&xn_sc[(size_t)s0 * 128 + c];
                uint4 u0b = *(const uint4*)&xn_sc[(size_t)s0 * 128 + c + 8];
                uint4 u1a = *(const uint4*)&xn_sc[(size_t)s1 * 128 + c];
                uint4 u1b = *(const uint4*)&xn_sc[(size_t)s1 * 128 + c + 8];
                acc8(u0a, a); acc8(u0b, a + 8);
                acc8(u1a, a); acc8(u1b, a + 8);
                e += 2;
            }
            if (e < e1) {
                int s0 = col[e];
                uint4 u0a = *(const uint4*)&xn_sc[(size_t)s0 * 128 + c];
                uint4 u0b = *(const uint4*)&xn_sc[(size_t)s0 * 128 + c + 8];
                acc8(u0a, a); acc8(u0b, a + 8);
            }
        }
        uint4 p0 = make_uint4((uint)f2bf(a[0]) | ((uint)f2bf(a[1]) << 16),
                              (uint)f2bf(a[2]) | ((uint)f2bf(a[3]) << 16),
                              (uint)f2bf(a[4]) | ((uint)f2bf(a[5]) << 16),
                              (uint)f2bf(a[6]) | ((uint)f2bf(a[7]) << 16));
        uint4 p1 = make_uint4((uint)f2bf(a[8])  | ((uint)f2bf(a[9])  << 16),
                              (uint)f2bf(a[10]) | ((uint)f2bf(a[11]) << 16),
                              (uint)f2bf(a[12]) | ((uint)f2bf(a[13]) << 16),
                              (uint)f2bf(a[14]) | ((uint)f2bf(a[15]) << 16));
        int G0 = 2 * l, G1 = 2 * l + 1;
        char* base = (char*)As + rl * 256;
        *(uint4*)(base + (G0 >> 3) * 128 + (((G0 & 7) ^ (rl & 7)) << 4)) = p0;
        *(uint4*)(base + (G1 >> 3) * 128 + (((G1 & 7) ^ (rl & 7)) << 4)) = p1;
    }
    // (phase-1's first __syncthreads makes the gathered tile visible before reads)

    // ---------------- phase 1: conv1 ----------------
    f32x4 acc[2][4];
    f32x4 zero = {0.f, 0.f, 0.f, 0.f};
    #pragma unroll
    for (int m = 0; m < 2; m++)
        #pragma unroll
        for (int nn = 0; nn < 4; nn++) acc[m][nn] = zero;

    for (int ks = 0; ks < 2; ks++) {
        #pragma unroll
        for (int c = 0; c < 4; c++) {
            int gB = w * 256 + c * 64 + lane;
            int rB = gB >> 3, lcB = gB & 7;
            stage16(W1T + (size_t)rB * 128 + ks * 64 + ((lcB ^ (rB & 7)) << 3), Bs + gB * 8);
        }
        __syncthreads();
        const char* ab = (const char*)As;
        const char* bb = (const char*)Bs;
        #pragma unroll
        for (int kk = 0; kk < 2; kk++) {
            int kx = (((kk * 4 + lk) ^ sw) << 4);
            bf16x8 af[2], bf[4];
            #pragma unroll
            for (int m = 0; m < 2; m++) {
                int r = wm * 32 + m * 16 + lr;
                af[m] = *(const bf16x8*)(ab + r * 256 + ks * 128 + kx);
            }
            #pragma unroll
            for (int nn = 0; nn < 2; nn++) {
                int vrow = h * 128 + pbase + nn * 16 + lr;
                bf[nn]     = *(const bf16x8*)(bb + vrow * 128 + kx);
                bf[nn + 2] = *(const bf16x8*)(bb + (vrow + 64) * 128 + kx);
            }
            #pragma unroll
            for (int m = 0; m < 2; m++)
                #pragma unroll
                for (int nn = 0; nn < 4; nn++)
                    acc[m][nn] = __builtin_amdgcn_mfma_f32_16x16x32_bf16(af[m], bf[nn], acc[m][nn], 0, 0, 0);
        }
        __syncthreads();
    }

    // ---------------- phase-1 epilogue: out[:,128:256] + Qs (swizzled LDS) ----------------
    #pragma unroll
    for (int m = 0; m < 2; m++) {
        int rloc0 = wm * 32 + m * 16 + lk * 4;
        #pragma unroll
        for (int nn = 0; nn < 2; nn++) {
            int po = pbase + nn * 16 + lr;
            int cv = h * 64 + po;                 // pair/v-col 0..127
            float biv = bias_cat[h * 128 + po];
            float bit = bias_cat[h * 128 + 64 + po];
            #pragma unroll
            for (int j = 0; j < 4; j++) {
                int rl = rloc0 + j;
                int r  = row0 + rl;
                float lv = 0.f, lt = 0.f;
                if (r < n) {
                    float win = inrm[r];
                    float won = onrm[r];
                    float ge = bf2f((uint)gid[(size_t)r * 128 + cv]);
                    float tv = acc[m][nn][j] * win + biv + ge;
                    float tt = acc[m][nn + 2][j] * win + bit + ge;
                    lv = lrelu(tv); lt = lrelu(tt);
                    out[(size_t)r * 384 + 128 + cv] = 0.5f * (lv + lt);
                    lv *= won; lt *= won;
                }
                uint pk = (uint)f2bf(lv) | ((uint)f2bf(lt) << 16);
                *(uint*)((char*)Qs + ((rl * 512 + 4 * cv) ^ ((rl & 7) << 4))) = pk;
            }
        }
    }
    // reg-stage phase 2 A (k 0:128): lrelu(xn_sc) into As halves (same granule mapping
    // the DMA used: granule gA -> row rA, swizzled source col scolA)
    int gA = w * 64 + lane;
    int rA = gA >> 3, lcA = gA & 7;
    int scolA = ((lcA ^ (rA & 7)) << 3);
    int dA = gA * 8;
    {
        int rg = row0 + rA;
        #pragma unroll
        for (int ks = 0; ks < 2; ks++) {
            uint4 u = make_uint4(0u, 0u, 0u, 0u);
            if (rg < n) u = *(const uint4*)&xn_sc[(size_t)rg * 128 + scolA + ks * 64];
            u.x = lrelu_pk(u.x); u.y = lrelu_pk(u.y);
            u.z = lrelu_pk(u.z); u.w = lrelu_pk(u.w);
            *(uint4*)&As[ks * 4096 + dA] = u;
        }
    }
    #pragma unroll
    for (int c = 0; c < 2; c++) {
        int g2 = w * 128 + c * 64 + lane;
        int r2 = g2 >> 3, lc2 = g2 & 7;
        stage16(W2T + (size_t)r2 * 384 + ((lc2 ^ (r2 & 7)) << 3), Bs + g2 * 8);
    }
    __syncthreads();   // Qs + As ds_writes + DMA staged all visible

    // ---------------- phase 2: q = [lrelu(xn_sc) | Qs] @ W2, K=384 ----------------
    f32x4 acc2[2][2];
    #pragma unroll
    for (int m = 0; m < 2; m++)
        #pragma unroll
        for (int nn = 0; nn < 2; nn++) acc2[m][nn] = zero;

    for (int s = 0; s < 6; s++) {
        if (s < 5) {                              // stage next W2 k-step into other half
            int nh = (s + 1) & 1;
            #pragma unroll
            for (int c = 0; c < 2; c++) {
                int g2 = w * 128 + c * 64 + lane;
                int r2 = g2 >> 3, lc2 = g2 & 7;
                stage16(W2T + (size_t)r2 * 384 + (s + 1) * 64 + ((lc2 ^ (r2 & 7)) << 3),
                        Bs + nh * 8192 + g2 * 8);
            }
        }
        const char* bb2 = (const char*)(Bs + (s & 1) * 8192);
        #pragma unroll
        for (int kk = 0; kk < 2; kk++) {
            int kx = (((kk * 4 + lk) ^ sw) << 4);
            bf16x8 af[2], bf[2];
            #pragma unroll
            for (int m = 0; m < 2; m++) {
                int rl = wm * 32 + m * 16 + lr;
                if (s < 2)
                    af[m] = *(const bf16x8*)((const char*)(As + s * 4096) + rl * 128 + kx);
                else
                    af[m] = *(const bf16x8*)((const char*)Qs +
                              ((rl * 512 + (s - 2) * 128 + (kk * 4 + lk) * 16) ^ ((rl & 7) << 4)));
            }
            #pragma unroll
            for (int nn = 0; nn < 2; nn++) {
                int cg = wn * 32 + nn * 16 + lr;
                bf[nn] = *(const bf16x8*)(bb2 + cg * 128 + kx);
            }
            #pragma unroll
            for (int m = 0; m < 2; m++)
                #pragma unroll
                for (int nn = 0; nn < 2; nn++)
                    acc2[m][nn] = __builtin_amdgcn_mfma_f32_16x16x32_bf16(af[m], bf[nn], acc2[m][nn], 0, 0, 0);
        }
        __syncthreads();   // next-step staging visible; this step's Bs reads done
    }

    // ---------------- phase-2 epilogue: q (bf16) ----------------
    #pragma unroll
    for (int m = 0; m < 2; m++) {
        int rb = row0 + wm * 32 + m * 16 + lk * 4;
        #pragma unroll
        for (int nn = 0; nn < 2; nn++) {
            int cg = wn * 32 + nn * 16 + lr;
            #pragma unroll
            for (int j = 0; j < 4; j++) {
                int r = rb + j;
                if (r < n) q[(size_t)r * 128 + cg] = f2bf(acc2[m][nn][j]);
            }
        }
    }
}

extern "C" void kernel_launch(void* const* d_in, const int* in_sizes, int n_in,
                              void* d_out, int out_size, void* d_ws, size_t ws_size,
                              hipStream_t stream) {
    const float* x      = (const float*)d_in[0];
    const float* id_emb = (const float*)d_in[1];
    const float* Wv0    = (const float*)d_in[2];
    const float* bv0    = (const float*)d_in[3];
    const float* Wv1    = (const float*)d_in[4];
    const float* bv1    = (const float*)d_in[5];
    const float* Wt0    = (const float*)d_in[6];
    const float* bt0    = (const float*)d_in[7];
    const float* Wt1    = (const float*)d_in[8];
    const float* bt1    = (const float*)d_in[9];
    const int*   src    = (const int*)d_in[10];
    const int*   dst    = (const int*)d_in[11];
    const int*   dsti   = (const int*)d_in[12];
    const int E = in_sizes[10];
    const int N = in_sizes[12];
    float* out = (float*)d_out;

    char* p = (char*)d_ws;
    ushort* xn_sc   = (ushort*)p; p += (size_t)N * 128 * 2;
    ushort* q       = (ushort*)p; p += (size_t)N * 128 * 2;
    ushort* gid     = (ushort*)p; p += (size_t)N * 128 * 2;
    ushort* W1T     = (ushort*)p; p += 256 * 128 * 2;
    ushort* W2T     = (ushort*)p; p += 128 * 384 * 2;
    float* bias_cat = (float*)p;  p += 256 * 4;
    float* bias2    = (float*)p;  p += 128 * 4;
    float* onrm     = (float*)p;  p += (size_t)N * 4;
    float* inrm     = (float*)p;  p += (size_t)N * 4;
    int* deg_out    = (int*)p;    p += (size_t)N * 4;
    int* deg_in     = (int*)p;    p += (size_t)N * 4;
    int* cursor     = (int*)p;    p += (size_t)N * 4;
    int* row_ptr    = (int*)p;    p += (size_t)(N + 1) * 4;
    int* csum       = (int*)p;    p += 1024 * 4;
    int* col        = (int*)p;    p += (size_t)E * 4;

    hipMemsetAsync(deg_out, 0, (size_t)N * 2 * 4, stream);   // deg_out|deg_in contiguous

    int be = (E + 255) / 256;
    int bn = (N + 255) / 256;
    int bq = (N * 16 + 255) / 256;          // 16-lane groups (normx + agg2e)
    int bc = (N + 63) / 64;                 // 64-row fused-conv tiles
    int nb = (N + 1023) / 1024;             // scan chunks

    k_degprep<<<192 + be, 256, 0, stream>>>(src, dst, deg_out, deg_in, E,
                                            Wv0, Wt0, Wv1, Wt1, bv0, bt0, bv1, bt1,
                                            W1T, W2T, bias_cat, bias2);
    k_scan1  <<<nb, 1024, 0, stream>>>(deg_out, deg_in, row_ptr, csum, onrm, inrm, N);
    k_scan3  <<<bn, 256, 0, stream>>>(row_ptr, csum, cursor, N);
    k_fill   <<<be, 256, 0, stream>>>(src, dst, cursor, col, E);
    k_normx  <<<bq, 256, 0, stream>>>(x, onrm, dsti, id_emb, xn_sc, gid, out, N);

    k_conv <<<bc, 512, 0, stream>>>(xn_sc, row_ptr, col, W1T, W2T,
                                    inrm, onrm, gid, bias_cat, q, out, N);
    k_agg2e<<<bq, 256, 0, stream>>>(q, row_ptr, col, inrm, bias2, gid, out, N);
}